// Round 3
// baseline (796.034 us; speedup 1.0000x reference)
//
#include <hip/hip_runtime.h>

typedef __attribute__((ext_vector_type(8))) short short8;
typedef __attribute__((ext_vector_type(8))) unsigned short ushort8_t;
typedef __attribute__((ext_vector_type(4))) float floatx4;
typedef __attribute__((ext_vector_type(2))) _Float16 half2_t;
typedef __attribute__((ext_vector_type(4))) _Float16 half4;
typedef __attribute__((ext_vector_type(8))) _Float16 half8;
typedef __attribute__((ext_vector_type(2))) unsigned int uint2v;

#define B_ 4
#define S_ 2048
#define D_ 1024
#define H_ 16
#define DK_ 64
#define BS_ (B_ * S_)   // 8192

union V8u { half8 v8; half4 v4[2]; };
union H16 { _Float16 h; unsigned short u; };

typedef const __attribute__((address_space(1))) void* gvp;
typedef __attribute__((address_space(3))) void* lvp;

// ---------- helpers ----------
static __device__ __forceinline__ unsigned short f2bf(float f) {
  union { float f; unsigned int u; } x; x.f = f;
  unsigned int r = x.u + 0x7fffu + ((x.u >> 16) & 1u);   // RNE
  return (unsigned short)(r >> 16);
}

static __device__ __forceinline__ half2_t pk_f16(float a, float b) {
  return __builtin_bit_cast(half2_t, __builtin_amdgcn_cvt_pkrtz(a, b));
}

// raw hardware exp2: avoids the OCML denormal-correct wrapper (~5x cheaper).
static __device__ __forceinline__ float fexp2(float x) {
  float r;
  asm("v_exp_f32 %0, %1" : "=v"(r) : "v"(x));
  return r;
}

static __device__ __forceinline__ half8 mk8(uint2v a, uint2v b) {
  union { unsigned u[4]; half8 h; } t;
  t.u[0] = a.x; t.u[1] = a.y; t.u[2] = b.x; t.u[3] = b.y;
  return t.h;
}

// ---------- fused input casts (q/k/v) ----------
__global__ void cast3_kernel(const float* __restrict__ a, const float* __restrict__ b,
                             const float* __restrict__ c,
                             unsigned short* __restrict__ oa, unsigned short* __restrict__ ob,
                             unsigned short* __restrict__ oc, int n4) {
  int i = blockIdx.x * blockDim.x + threadIdx.x;
  int w = blockIdx.y;
  const float* src = (w == 0) ? a : (w == 1) ? b : c;
  unsigned short* dst = (w == 0) ? oa : (w == 1) ? ob : oc;
  if (i < n4) {
    float4 v = ((const float4*)src)[i];
    ushort4 o;
    o.x = f2bf(v.x); o.y = f2bf(v.y); o.z = f2bf(v.z); o.w = f2bf(v.w);
    ((ushort4*)dst)[i] = o;
  }
}

// fused 4-weight cast
__global__ void cast4_kernel(const float* __restrict__ a, const float* __restrict__ b,
                             const float* __restrict__ c, const float* __restrict__ d,
                             unsigned short* __restrict__ oa, unsigned short* __restrict__ ob,
                             unsigned short* __restrict__ oc, unsigned short* __restrict__ od, int n4) {
  int i = blockIdx.x * blockDim.x + threadIdx.x;
  int w = blockIdx.y;
  const float* src = (w == 0) ? a : (w == 1) ? b : (w == 2) ? c : d;
  unsigned short* dst = (w == 0) ? oa : (w == 1) ? ob : (w == 2) ? oc : od;
  if (i < n4) {
    float4 v = ((const float4*)src)[i];
    ushort4 o;
    o.x = f2bf(v.x); o.y = f2bf(v.y); o.z = f2bf(v.z); o.w = f2bf(v.w);
    ((ushort4*)dst)[i] = o;
  }
}

// ---------- mask int32 -> bitmask (bit=1 means keep) ----------
__global__ void pack_mask(const int* __restrict__ mask, unsigned long long* __restrict__ bits) {
  int i = blockIdx.x * blockDim.x + threadIdx.x;
  unsigned long long m = __ballot(mask[i] != 0);
  if ((threadIdx.x & 63) == 0) bits[i >> 6] = m;
}

// ---------- V [B,H,S,64] (f16) -> Vt [B,H,64,S] (f16), k-permuted per 64-block ----------
__global__ void transpose_v(const unsigned short* __restrict__ Vh, unsigned short* __restrict__ Vt) {
  __shared__ unsigned short T[64][72];
  int bh = blockIdx.y;
  int s0 = blockIdx.x * 64;
  int tid = threadIdx.x;
  int r = tid >> 3, c = (tid & 7) * 8;
  const unsigned short* src = Vh + ((size_t)bh * S_ + s0) * DK_;
#pragma unroll
  for (int p = 0; p < 2; ++p)
    *(uint4*)(&T[r + p * 32][c]) = *(const uint4*)(src + (size_t)(r + p * 32) * DK_ + c);
  __syncthreads();
  unsigned short* dst = Vt + (size_t)bh * DK_ * S_;
#pragma unroll
  for (int p = 0; p < 2; ++p) {
    int d = r + p * 32;
    ushort8_t o;
#pragma unroll
    for (int i = 0; i < 8; ++i) {
      int pos = c + i;
      int th = pos >> 5, rem = pos & 31;
      int q4 = rem >> 3, rem2 = rem & 7;
      int t = th * 2 + (rem2 >> 2), j = rem2 & 3;
      int k = t * 16 + q4 * 4 + j;
      o[i] = T[k][d];
    }
    *(ushort8_t*)(dst + (size_t)d * S_ + s0 + c) = o;
  }
}

// ---------- pipelined GEMM core: Y = scale*(X(Mx1024) * W(1024x1024)^T + bias) ----------
__device__ __forceinline__ void gemm_core(
    const unsigned short* __restrict__ X, const unsigned short* __restrict__ W,
    const float* __restrict__ bias, void* __restrict__ Y,
    float scale, int mode, int bm, int bn,
    unsigned short* As, unsigned short* Bs)
{
  constexpr int K = D_, N = D_;
  int tid = threadIdx.x;
  int wave = tid >> 6, lane = tid & 63, quad = lane >> 4, li = lane & 15;
  int wm = wave >> 1, wn = wave & 1;
  int srow = lane >> 3;
  int scol = ((lane & 7) ^ srow) * 8;   // XOR swizzle on global side
  const unsigned short* gA = X + (size_t)(bm * 128 + wave * 32 + srow) * K + scol;
  const unsigned short* gB = W + (size_t)(bn * 128 + wave * 32 + srow) * K + scol;

  auto stage = [&](int buf, int k0) {
#pragma unroll
    for (int j = 0; j < 4; ++j) {
      __builtin_amdgcn_global_load_lds((gvp)(gA + (size_t)(j * 8) * K + k0),
          (lvp)(As + buf * 8192 + wave * 2048 + j * 512), 16, 0, 0);
      __builtin_amdgcn_global_load_lds((gvp)(gB + (size_t)(j * 8) * K + k0),
          (lvp)(Bs + buf * 8192 + wave * 2048 + j * 512), 16, 0, 0);
    }
  };

  floatx4 acc[4][4] = {};
  stage(0, 0);
  constexpr int NK = K / 64;
  for (int i = 0; i < NK; ++i) {
    int buf = i & 1;
    __syncthreads();                       // buf data valid; prev prefetch already landed
    if (i + 1 < NK) stage(buf ^ 1, (i + 1) * 64);   // prefetch next tile (hidden behind compute)
    short8 af[2][4], bf[2][4];
#pragma unroll
    for (int s2 = 0; s2 < 2; ++s2)
#pragma unroll
      for (int t = 0; t < 4; ++t) {
        int slot = ((s2 * 4 + quad) ^ (li & 7)) * 8;
        af[s2][t] = *(const short8*)(&As[buf * 8192 + (wm * 64 + t * 16 + li) * 64 + slot]);
        bf[s2][t] = *(const short8*)(&Bs[buf * 8192 + (wn * 64 + t * 16 + li) * 64 + slot]);
      }
#pragma unroll
    for (int s2 = 0; s2 < 2; ++s2)
#pragma unroll
      for (int mt = 0; mt < 4; ++mt)
#pragma unroll
        for (int nt = 0; nt < 4; ++nt)
          acc[mt][nt] = __builtin_amdgcn_mfma_f32_16x16x32_bf16(af[s2][mt], bf[s2][nt], acc[mt][nt], 0, 0, 0);
  }

#pragma unroll
  for (int nt = 0; nt < 4; ++nt) {
    int n = bn * 128 + wn * 64 + nt * 16 + li;
    float bv = bias[n];
#pragma unroll
    for (int mt = 0; mt < 4; ++mt) {
#pragma unroll
      for (int r = 0; r < 4; ++r) {
        int m = bm * 128 + wm * 64 + mt * 16 + quad * 4 + r;
        float v = (acc[mt][nt][r] + bv) * scale;
        if (mode == 1) {
          ((float*)Y)[(size_t)m * N + n] = v;
        } else {
          int b = m >> 11, s = m & 2047, h = n >> 6, dk = n & 63;
          size_t idx = (((size_t)(b * H_ + h)) * S_ + s) * DK_ + dk;
          if (mode == 0) {
            ((unsigned short*)Y)[idx] = f2bf(v);
          } else {
            H16 hv; hv.h = (_Float16)v;
            ((unsigned short*)Y)[idx] = hv.u;
          }
        }
      }
    }
  }
}

__global__ __launch_bounds__(256) void gemm_qkv(
    const unsigned short* __restrict__ Xq, const unsigned short* __restrict__ Xk,
    const unsigned short* __restrict__ Xv,
    const unsigned short* __restrict__ Wq, const unsigned short* __restrict__ Wk,
    const unsigned short* __restrict__ Wv,
    const float* __restrict__ bq, const float* __restrict__ bk, const float* __restrict__ bv,
    unsigned short* __restrict__ Qh, unsigned short* __restrict__ Kh,
    unsigned short* __restrict__ Vh, float sc)
{
  __shared__ __align__(16) unsigned short As[2 * 8192];
  __shared__ __align__(16) unsigned short Bs[2 * 8192];
  int z = blockIdx.z;
  const unsigned short* X = (z == 0) ? Xq : (z == 1) ? Xk : Xv;
  const unsigned short* W = (z == 0) ? Wq : (z == 1) ? Wk : Wv;
  const float* bias = (z == 0) ? bq : (z == 1) ? bk : bv;
  void* Y = (z == 0) ? (void*)Qh : (z == 1) ? (void*)Kh : (void*)Vh;
  float scale = (z == 0) ? sc : 1.0f;
  int mode = (z == 2) ? 2 : 0;
  gemm_core(X, W, bias, Y, scale, mode, blockIdx.y, blockIdx.x, As, Bs);
}

__global__ __launch_bounds__(256) void gemm_out(
    const unsigned short* __restrict__ X, const unsigned short* __restrict__ W,
    const float* __restrict__ bias, float* __restrict__ Y)
{
  __shared__ __align__(16) unsigned short As[2 * 8192];
  __shared__ __align__(16) unsigned short Bs[2 * 8192];
  gemm_core(X, W, bias, Y, 1.0f, 1, blockIdx.y, blockIdx.x, As, Bs);
}

// ---------- flash attention: triple-buffered, counted-vmcnt pipeline ----------
// 8 waves / 512 threads per block; 256 q-rows per block; grid = 64 bh x 8 qb = 512
// (2 blocks/CU, LDS 48.2KB -> both resident). K/V staged 2 tiles ahead into a rotating
// 3-buffer via global_load_lds; per-iter VMEM = stage(2) + masks(2) = 4 ops, so
// "s_waitcnt vmcnt(4)" before s_barrier guarantees tile-i's stage landed while tiles
// i+1/i+2 stay in flight. NO vmcnt(0) drain anywhere in the main loop (T3+T4).
__global__ __launch_bounds__(512, 4) void attn_kernel(
    const unsigned short* __restrict__ Qh,
    const unsigned short* __restrict__ Kh,
    const _Float16* __restrict__ Vt,
    const unsigned long long* __restrict__ mbits,
    unsigned short* __restrict__ attnb)
{
  __shared__ __align__(16) unsigned short Ks[3 * 4096];
  __shared__ __align__(16) unsigned short Vs[3 * 4096];
  __shared__ __align__(8) uint2v mlut[16];   // nibble -> 2x32b AND-masks for packed f16 pairs

  int tid = threadIdx.x;
  int wave = tid >> 6, lane = tid & 63, quad = lane >> 4, li = lane & 15;

  // every wave writes the same values: no cross-wave dependency on this init
  // (raw s_barrier does not drain lgkm like __syncthreads did)
  if (lane < 16) {
    unsigned nb = (unsigned)lane;
    uint2v m;
    m.x = (nb & 1u ? 0x0000FFFFu : 0u) | (nb & 2u ? 0xFFFF0000u : 0u);
    m.y = (nb & 4u ? 0x0000FFFFu : 0u) | (nb & 8u ? 0xFFFF0000u : 0u);
    mlut[nb] = m;
  }

  int blk = blockIdx.x;
  int xcd = blk & 7, slot = blk >> 3;          // 64 slots per XCD
  int bh = xcd * 8 + (slot >> 3);
  int qb = slot & 7;
  int b = bh >> 4, h = bh & 15;
  int qbase = qb * 256 + wave * 32;
  const size_t hq = (size_t)bh * S_ * DK_;

  // Q fragments (B-operand of S^T mfma), loaded once from global
  short8 aQ[2][2];
#pragma unroll
  for (int qs = 0; qs < 2; ++qs)
#pragma unroll
    for (int s2 = 0; s2 < 2; ++s2)
      aQ[qs][s2] = *(const short8*)(Qh + hq + (size_t)(qbase + qs * 16 + li) * DK_ + s2 * 32 + quad * 8);

  floatx4 o[2][4] = {};
  floatx4 lacc[2] = {};
  const half8 ones8 = {(_Float16)1.f, (_Float16)1.f, (_Float16)1.f, (_Float16)1.f,
                       (_Float16)1.f, (_Float16)1.f, (_Float16)1.f, (_Float16)1.f};

  const unsigned long long* mrow = mbits + ((size_t)b * S_ + qbase + li) * (S_ / 64);

  // staging: 8 waves x 8 rows each cover the 64-row K/V tile; 1 load per wave per array
  int srow = lane >> 3;
  int scol = ((lane & 7) ^ srow) * 8;   // XOR swizzle on global side
  const unsigned short* gK = Kh + hq + (size_t)(wave * 8 + srow) * DK_ + scol;
  const _Float16* gV = Vt + ((size_t)bh * 64 + wave * 8 + srow) * S_ + scol;

  auto stage = [&](int o3, int kb) {
    __builtin_amdgcn_global_load_lds((gvp)(gK + (size_t)(kb * 64) * DK_),
        (lvp)(Ks + o3 + wave * 512), 16, 0, 0);
    __builtin_amdgcn_global_load_lds((gvp)(gV + (size_t)(kb * 64)),
        (lvp)(Vs + o3 + wave * 512), 16, 0, 0);
  };

  // prologue: 2-deep prefetch, then masks (order matters for the vmcnt count)
  stage(0, 0);
  stage(4096, 1);
  unsigned long long mw0c = mrow[0];
  unsigned long long mw1c = mrow[16 * (S_ / 64)];

  int o0 = 0, o1 = 4096, o2 = 8192;   // rotating buffer offsets (ushorts)

  constexpr int NK = S_ / 64;
  for (int i = 0; i < NK; ++i) {
    // tile i's stage (issued 2 iters ago) has exactly 4 newer VMEM ops
    // (stage i+1: 2, masks: 2) -> vmcnt(4) proves it landed, keeps the rest in flight.
    asm volatile("s_waitcnt vmcnt(4)" ::: "memory");
    __builtin_amdgcn_s_barrier();
    __builtin_amdgcn_sched_barrier(0);

    if (i + 2 < NK) stage(o2, i + 2);
    unsigned long long mw0n = 0, mw1n = 0;
    if (i + 1 < NK) { mw0n = mrow[i + 1]; mw1n = mrow[16 * (S_ / 64) + i + 1]; }

    // K fragments from LDS (unswizzle)
    short8 bK[4][2];
#pragma unroll
    for (int t = 0; t < 4; ++t)
#pragma unroll
      for (int s2 = 0; s2 < 2; ++s2)
        bK[t][s2] = *(const short8*)(&Ks[o0 + (t * 16 + li) * 64 + (((s2 * 4 + quad) ^ (li & 7)) * 8)]);

    // V fragments from LDS (unswizzle)
    V8u vv[4][2];
#pragma unroll
    for (int dt = 0; dt < 4; ++dt)
#pragma unroll
      for (int tp = 0; tp < 2; ++tp)
        vv[dt][tp].v8 = *(const half8*)((const _Float16*)&Vs[o0 + (dt * 16 + li) * 64 + (((tp * 4 + quad) ^ (li & 7)) * 8)]);

    // scores transposed: lane holds S[q=li][k = i*64 + t*16 + quad*4 + r]
    floatx4 sc[4][2] = {};
    __builtin_amdgcn_s_setprio(1);
#pragma unroll
    for (int s2 = 0; s2 < 2; ++s2)
#pragma unroll
      for (int t = 0; t < 4; ++t)
#pragma unroll
        for (int qs = 0; qs < 2; ++qs)
          sc[t][qs] = __builtin_amdgcn_mfma_f32_16x16x32_bf16(bK[t][s2], aQ[qs][s2], sc[t][qs], 0, 0, 0);
    __builtin_amdgcn_s_setprio(0);

    unsigned long long sh0 = mw0c >> (quad * 4);
    unsigned long long sh1 = mw1c >> (quad * 4);

    // softmax without max-subtraction (exp2-domain scores):
    // P = exp2(s) packed to f16, then AND-masked via nibble LUT (masked lanes -> 0.0)
    uint2v aPu[4][2];
#pragma unroll
    for (int t = 0; t < 4; ++t)
#pragma unroll
      for (int qs = 0; qs < 2; ++qs) {
        unsigned nb = (unsigned)(((qs ? sh1 : sh0) >> (t * 16)) & 15u);
        uint2v mm = mlut[nb];
        float p0 = fexp2(sc[t][qs][0]);
        float p1 = fexp2(sc[t][qs][1]);
        float p2 = fexp2(sc[t][qs][2]);
        float p3 = fexp2(sc[t][qs][3]);
        uint2v pp;
        pp.x = __builtin_bit_cast(unsigned, pk_f16(p0, p1)) & mm.x;
        pp.y = __builtin_bit_cast(unsigned, pk_f16(p2, p3)) & mm.y;
        aPu[t][qs] = pp;
      }

    // PV + row-sum l on the MFMA pipe, K=32 f16 mfma (t-pairs merged)
    __builtin_amdgcn_s_setprio(1);
#pragma unroll
    for (int a = 0; a < 2; ++a)
#pragma unroll
      for (int qs = 0; qs < 2; ++qs) {
        half8 pa = mk8(aPu[2 * a][qs], aPu[2 * a + 1][qs]);
        lacc[qs] = __builtin_amdgcn_mfma_f32_16x16x32_f16(pa, ones8, lacc[qs], 0, 0, 0);
#pragma unroll
        for (int dt = 0; dt < 4; ++dt)
          o[qs][dt] = __builtin_amdgcn_mfma_f32_16x16x32_f16(pa, vv[dt][a].v8, o[qs][dt], 0, 0, 0);
      }
    __builtin_amdgcn_s_setprio(0);

    mw0c = mw0n; mw1c = mw1n;
    int tb = o0; o0 = o1; o1 = o2; o2 = tb;
  }

  // lacc[qs][r] = l for q-row (qs*16 + quad*4 + r), replicated across li -> no shuffles needed
#pragma unroll
  for (int qs = 0; qs < 2; ++qs)
#pragma unroll
    for (int r = 0; r < 4; ++r) {
      float ir = 1.0f / lacc[qs][r];
      size_t row = (size_t)b * S_ + qbase + qs * 16 + quad * 4 + r;
#pragma unroll
      for (int dt = 0; dt < 4; ++dt)
        attnb[row * D_ + h * DK_ + dt * 16 + li] = f2bf(o[qs][dt][r] * ir);
    }
}

// ---------- host ----------
extern "C" void kernel_launch(void* const* d_in, const int* in_sizes, int n_in,
                              void* d_out, int out_size, void* d_ws, size_t ws_size,
                              hipStream_t stream) {
  const float* query = (const float*)d_in[0];
  const float* key   = (const float*)d_in[1];
  const float* value = (const float*)d_in[2];
  const int*   mask  = (const int*)d_in[3];
  const float* Wq = (const float*)d_in[4];
  const float* bq = (const float*)d_in[5];
  const float* Wk = (const float*)d_in[6];
  const float* bk = (const float*)d_in[7];
  const float* Wv = (const float*)d_in[8];
  const float* bv = (const float*)d_in[9];
  const float* Wo = (const float*)d_in[10];
  const float* bo = (const float*)d_in[11];
  float* out = (float*)d_out;

  char* ws = (char*)d_ws;
  size_t off = 0;
  auto alloc = [&](size_t bytes) -> void* {
    void* p = ws + off;
    off += (bytes + 255) & ~(size_t)255;
    return p;
  };
  unsigned short* Xq    = (unsigned short*)alloc((size_t)BS_ * D_ * 2);
  unsigned short* Xk    = (unsigned short*)alloc((size_t)BS_ * D_ * 2);
  unsigned short* Xv    = (unsigned short*)alloc((size_t)BS_ * D_ * 2);
  unsigned short* Wqb   = (unsigned short*)alloc((size_t)D_ * D_ * 2);
  unsigned short* Wkb   = (unsigned short*)alloc((size_t)D_ * D_ * 2);
  unsigned short* Wvb   = (unsigned short*)alloc((size_t)D_ * D_ * 2);
  unsigned short* Wob   = (unsigned short*)alloc((size_t)D_ * D_ * 2);
  unsigned short* Qh    = (unsigned short*)alloc((size_t)BS_ * D_ * 2);
  unsigned short* Kh    = (unsigned short*)alloc((size_t)BS_ * D_ * 2);
  unsigned short* Vh    = (unsigned short*)alloc((size_t)BS_ * D_ * 2);  // f16 bits
  unsigned short* Vt    = (unsigned short*)alloc((size_t)BS_ * D_ * 2);  // f16 bits
  unsigned short* attnb = (unsigned short*)alloc((size_t)BS_ * D_ * 2);
  unsigned long long* mbits = (unsigned long long*)alloc((size_t)B_ * S_ * (S_ / 64) * 8);

  const float SC = 0.18033688011112042f;  // (1/8) * log2(e), folded into Q

  pack_mask<<<(B_ * S_ * S_) / 256, 256, 0, stream>>>(mask, mbits);

  int wn4 = D_ * D_ / 4;
  cast4_kernel<<<dim3(wn4 / 256, 4), 256, 0, stream>>>(Wq, Wk, Wv, Wo, Wqb, Wkb, Wvb, Wob, wn4);

  int xn4 = BS_ * D_ / 4;
  cast3_kernel<<<dim3(xn4 / 256, 3), 256, 0, stream>>>(query, key, value, Xq, Xk, Xv, xn4);

  gemm_qkv<<<dim3(D_ / 128, BS_ / 128, 3), 256, 0, stream>>>(
      Xq, Xk, Xv, Wqb, Wkb, Wvb, bq, bk, bv, Qh, Kh, Vh, SC);

  transpose_v<<<dim3(S_ / 64, B_ * H_), 256, 0, stream>>>(Vh, Vt);

  attn_kernel<<<dim3(512), 512, 0, stream>>>(Qh, Kh, (const _Float16*)Vt, mbits, attnb);

  gemm_out<<<dim3(D_ / 128, BS_ / 128), 256, 0, stream>>>(attnb, Wob, bo, out);
}

// Round 4
// 452.794 us; speedup vs baseline: 1.7580x; 1.7580x over previous
//
#include <hip/hip_runtime.h>

typedef __attribute__((ext_vector_type(8))) short short8;
typedef __attribute__((ext_vector_type(8))) unsigned short ushort8_t;
typedef __attribute__((ext_vector_type(4))) float floatx4;
typedef __attribute__((ext_vector_type(2))) _Float16 half2_t;
typedef __attribute__((ext_vector_type(4))) _Float16 half4;
typedef __attribute__((ext_vector_type(8))) _Float16 half8;
typedef __attribute__((ext_vector_type(2))) unsigned int uint2v;

#define B_ 4
#define S_ 2048
#define D_ 1024
#define H_ 16
#define DK_ 64
#define BS_ (B_ * S_)   // 8192

union V8u { half8 v8; half4 v4[2]; };
union H16 { _Float16 h; unsigned short u; };

typedef const __attribute__((address_space(1))) void* gvp;
typedef __attribute__((address_space(3))) void* lvp;

// ---------- helpers ----------
static __device__ __forceinline__ unsigned short f2bf(float f) {
  union { float f; unsigned int u; } x; x.f = f;
  unsigned int r = x.u + 0x7fffu + ((x.u >> 16) & 1u);   // RNE
  return (unsigned short)(r >> 16);
}

static __device__ __forceinline__ half2_t pk_f16(float a, float b) {
  return __builtin_bit_cast(half2_t, __builtin_amdgcn_cvt_pkrtz(a, b));
}

// raw hardware exp2: avoids the OCML denormal-correct wrapper (~5x cheaper).
static __device__ __forceinline__ float fexp2(float x) {
  float r;
  asm("v_exp_f32 %0, %1" : "=v"(r) : "v"(x));
  return r;
}

static __device__ __forceinline__ half8 mk8(uint2v a, uint2v b) {
  union { unsigned u[4]; half8 h; } t;
  t.u[0] = a.x; t.u[1] = a.y; t.u[2] = b.x; t.u[3] = b.y;
  return t.h;
}

// ---------- fused input casts (q/k/v) ----------
__global__ void cast3_kernel(const float* __restrict__ a, const float* __restrict__ b,
                             const float* __restrict__ c,
                             unsigned short* __restrict__ oa, unsigned short* __restrict__ ob,
                             unsigned short* __restrict__ oc, int n4) {
  int i = blockIdx.x * blockDim.x + threadIdx.x;
  int w = blockIdx.y;
  const float* src = (w == 0) ? a : (w == 1) ? b : c;
  unsigned short* dst = (w == 0) ? oa : (w == 1) ? ob : oc;
  if (i < n4) {
    float4 v = ((const float4*)src)[i];
    ushort4 o;
    o.x = f2bf(v.x); o.y = f2bf(v.y); o.z = f2bf(v.z); o.w = f2bf(v.w);
    ((ushort4*)dst)[i] = o;
  }
}

// fused 4-weight cast
__global__ void cast4_kernel(const float* __restrict__ a, const float* __restrict__ b,
                             const float* __restrict__ c, const float* __restrict__ d,
                             unsigned short* __restrict__ oa, unsigned short* __restrict__ ob,
                             unsigned short* __restrict__ oc, unsigned short* __restrict__ od, int n4) {
  int i = blockIdx.x * blockDim.x + threadIdx.x;
  int w = blockIdx.y;
  const float* src = (w == 0) ? a : (w == 1) ? b : (w == 2) ? c : d;
  unsigned short* dst = (w == 0) ? oa : (w == 1) ? ob : (w == 2) ? oc : od;
  if (i < n4) {
    float4 v = ((const float4*)src)[i];
    ushort4 o;
    o.x = f2bf(v.x); o.y = f2bf(v.y); o.z = f2bf(v.z); o.w = f2bf(v.w);
    ((ushort4*)dst)[i] = o;
  }
}

// ---------- mask int32 -> bitmask (bit=1 means keep) ----------
__global__ void pack_mask(const int* __restrict__ mask, unsigned long long* __restrict__ bits) {
  int i = blockIdx.x * blockDim.x + threadIdx.x;
  unsigned long long m = __ballot(mask[i] != 0);
  if ((threadIdx.x & 63) == 0) bits[i >> 6] = m;
}

// ---------- V [B,H,S,64] (f16) -> Vt [B,H,64,S] (f16), k-permuted per 64-block ----------
__global__ void transpose_v(const unsigned short* __restrict__ Vh, unsigned short* __restrict__ Vt) {
  __shared__ unsigned short T[64][72];
  int bh = blockIdx.y;
  int s0 = blockIdx.x * 64;
  int tid = threadIdx.x;
  int r = tid >> 3, c = (tid & 7) * 8;
  const unsigned short* src = Vh + ((size_t)bh * S_ + s0) * DK_;
#pragma unroll
  for (int p = 0; p < 2; ++p)
    *(uint4*)(&T[r + p * 32][c]) = *(const uint4*)(src + (size_t)(r + p * 32) * DK_ + c);
  __syncthreads();
  unsigned short* dst = Vt + (size_t)bh * DK_ * S_;
#pragma unroll
  for (int p = 0; p < 2; ++p) {
    int d = r + p * 32;
    ushort8_t o;
#pragma unroll
    for (int i = 0; i < 8; ++i) {
      int pos = c + i;
      int th = pos >> 5, rem = pos & 31;
      int q4 = rem >> 3, rem2 = rem & 7;
      int t = th * 2 + (rem2 >> 2), j = rem2 & 3;
      int k = t * 16 + q4 * 4 + j;
      o[i] = T[k][d];
    }
    *(ushort8_t*)(dst + (size_t)d * S_ + s0 + c) = o;
  }
}

// ---------- pipelined GEMM core: Y = scale*(X(Mx1024) * W(1024x1024)^T + bias) ----------
__device__ __forceinline__ void gemm_core(
    const unsigned short* __restrict__ X, const unsigned short* __restrict__ W,
    const float* __restrict__ bias, void* __restrict__ Y,
    float scale, int mode, int bm, int bn,
    unsigned short* As, unsigned short* Bs)
{
  constexpr int K = D_, N = D_;
  int tid = threadIdx.x;
  int wave = tid >> 6, lane = tid & 63, quad = lane >> 4, li = lane & 15;
  int wm = wave >> 1, wn = wave & 1;
  int srow = lane >> 3;
  int scol = ((lane & 7) ^ srow) * 8;   // XOR swizzle on global side
  const unsigned short* gA = X + (size_t)(bm * 128 + wave * 32 + srow) * K + scol;
  const unsigned short* gB = W + (size_t)(bn * 128 + wave * 32 + srow) * K + scol;

  auto stage = [&](int buf, int k0) {
#pragma unroll
    for (int j = 0; j < 4; ++j) {
      __builtin_amdgcn_global_load_lds((gvp)(gA + (size_t)(j * 8) * K + k0),
          (lvp)(As + buf * 8192 + wave * 2048 + j * 512), 16, 0, 0);
      __builtin_amdgcn_global_load_lds((gvp)(gB + (size_t)(j * 8) * K + k0),
          (lvp)(Bs + buf * 8192 + wave * 2048 + j * 512), 16, 0, 0);
    }
  };

  floatx4 acc[4][4] = {};
  stage(0, 0);
  constexpr int NK = K / 64;
  for (int i = 0; i < NK; ++i) {
    int buf = i & 1;
    __syncthreads();                       // buf data valid; prev prefetch already landed
    if (i + 1 < NK) stage(buf ^ 1, (i + 1) * 64);   // prefetch next tile (hidden behind compute)
    short8 af[2][4], bf[2][4];
#pragma unroll
    for (int s2 = 0; s2 < 2; ++s2)
#pragma unroll
      for (int t = 0; t < 4; ++t) {
        int slot = ((s2 * 4 + quad) ^ (li & 7)) * 8;
        af[s2][t] = *(const short8*)(&As[buf * 8192 + (wm * 64 + t * 16 + li) * 64 + slot]);
        bf[s2][t] = *(const short8*)(&Bs[buf * 8192 + (wn * 64 + t * 16 + li) * 64 + slot]);
      }
#pragma unroll
    for (int s2 = 0; s2 < 2; ++s2)
#pragma unroll
      for (int mt = 0; mt < 4; ++mt)
#pragma unroll
        for (int nt = 0; nt < 4; ++nt)
          acc[mt][nt] = __builtin_amdgcn_mfma_f32_16x16x32_bf16(af[s2][mt], bf[s2][nt], acc[mt][nt], 0, 0, 0);
  }

#pragma unroll
  for (int nt = 0; nt < 4; ++nt) {
    int n = bn * 128 + wn * 64 + nt * 16 + li;
    float bv = bias[n];
#pragma unroll
    for (int mt = 0; mt < 4; ++mt) {
#pragma unroll
      for (int r = 0; r < 4; ++r) {
        int m = bm * 128 + wm * 64 + mt * 16 + quad * 4 + r;
        float v = (acc[mt][nt][r] + bv) * scale;
        if (mode == 1) {
          ((float*)Y)[(size_t)m * N + n] = v;
        } else {
          int b = m >> 11, s = m & 2047, h = n >> 6, dk = n & 63;
          size_t idx = (((size_t)(b * H_ + h)) * S_ + s) * DK_ + dk;
          if (mode == 0) {
            ((unsigned short*)Y)[idx] = f2bf(v);
          } else {
            H16 hv; hv.h = (_Float16)v;
            ((unsigned short*)Y)[idx] = hv.u;
          }
        }
      }
    }
  }
}

__global__ __launch_bounds__(256) void gemm_qkv(
    const unsigned short* __restrict__ Xq, const unsigned short* __restrict__ Xk,
    const unsigned short* __restrict__ Xv,
    const unsigned short* __restrict__ Wq, const unsigned short* __restrict__ Wk,
    const unsigned short* __restrict__ Wv,
    const float* __restrict__ bq, const float* __restrict__ bk, const float* __restrict__ bv,
    unsigned short* __restrict__ Qh, unsigned short* __restrict__ Kh,
    unsigned short* __restrict__ Vh, float sc)
{
  __shared__ __align__(16) unsigned short As[2 * 8192];
  __shared__ __align__(16) unsigned short Bs[2 * 8192];
  int z = blockIdx.z;
  const unsigned short* X = (z == 0) ? Xq : (z == 1) ? Xk : Xv;
  const unsigned short* W = (z == 0) ? Wq : (z == 1) ? Wk : Wv;
  const float* bias = (z == 0) ? bq : (z == 1) ? bk : bv;
  void* Y = (z == 0) ? (void*)Qh : (z == 1) ? (void*)Kh : (void*)Vh;
  float scale = (z == 0) ? sc : 1.0f;
  int mode = (z == 2) ? 2 : 0;
  gemm_core(X, W, bias, Y, scale, mode, blockIdx.y, blockIdx.x, As, Bs);
}

__global__ __launch_bounds__(256) void gemm_out(
    const unsigned short* __restrict__ X, const unsigned short* __restrict__ W,
    const float* __restrict__ bias, float* __restrict__ Y)
{
  __shared__ __align__(16) unsigned short As[2 * 8192];
  __shared__ __align__(16) unsigned short Bs[2 * 8192];
  gemm_core(X, W, bias, Y, 1.0f, 1, blockIdx.y, blockIdx.x, As, Bs);
}

// ---------- flash attention: 256-thread, triple-buffered, counted-vmcnt pipeline ----------
// R2 structure (4 waves, 116 VGPR) + 2-deep prefetch. Per-iteration VMEM group is pinned
// by sched_barrier(0) to [mask(i+1): 2][stage(i+2): 4]; indices are CLAMPED (not guarded)
// so every iteration issues exactly 6 VMEM ops. Then s_waitcnt vmcnt(4) before each raw
// s_barrier retires tile i's stage+masks while keeping stage(i+1) (the 4 newest ops) in
// flight. No vmcnt(0) in the loop; each stage gets ~2 compute phases to land.
// Redundant tail stages land in the rotating buffer that is never read again (mod-3
// schedule + barrier ordering make this race-free).
__global__ __launch_bounds__(256) void attn_kernel(
    const unsigned short* __restrict__ Qh,
    const unsigned short* __restrict__ Kh,
    const _Float16* __restrict__ Vt,
    const unsigned long long* __restrict__ mbits,
    unsigned short* __restrict__ attnb)
{
  __shared__ __align__(16) unsigned short Ks[3 * 4096];
  __shared__ __align__(16) unsigned short Vs[3 * 4096];
  __shared__ __align__(8) uint2v mlut[16];   // nibble -> 2x32b AND-masks for packed f16 pairs

  int tid = threadIdx.x;
  int wave = tid >> 6, lane = tid & 63, quad = lane >> 4, li = lane & 15;

  // every wave writes the same values; intra-wave ds_write->ds_read dep is
  // handled by the compiler's lgkmcnt tracking (no cross-wave dependency).
  if (lane < 16) {
    unsigned nb = (unsigned)lane;
    uint2v m;
    m.x = (nb & 1u ? 0x0000FFFFu : 0u) | (nb & 2u ? 0xFFFF0000u : 0u);
    m.y = (nb & 4u ? 0x0000FFFFu : 0u) | (nb & 8u ? 0xFFFF0000u : 0u);
    mlut[nb] = m;
  }

  int blk = blockIdx.x;
  int xcd = blk & 7, slot7 = blk >> 3;
  int bh = xcd * 8 + (slot7 >> 4);
  int qb = slot7 & 15;
  int b = bh >> 4, h = bh & 15;
  int qbase = qb * 128 + wave * 32;
  const size_t hq = (size_t)bh * S_ * DK_;

  // Q fragments (B-operand of S^T mfma), loaded once from global
  short8 aQ[2][2];
#pragma unroll
  for (int qs = 0; qs < 2; ++qs)
#pragma unroll
    for (int s2 = 0; s2 < 2; ++s2)
      aQ[qs][s2] = *(const short8*)(Qh + hq + (size_t)(qbase + qs * 16 + li) * DK_ + s2 * 32 + quad * 8);

  floatx4 o[2][4] = {};
  floatx4 lacc[2] = {};
  const half8 ones8 = {(_Float16)1.f, (_Float16)1.f, (_Float16)1.f, (_Float16)1.f,
                       (_Float16)1.f, (_Float16)1.f, (_Float16)1.f, (_Float16)1.f};

  const unsigned long long* mrow = mbits + ((size_t)b * S_ + qbase + li) * (S_ / 64);

  // staging: wave w covers rows w*16..w*16+15; 4 VMEM ops per wave per tile
  int srow = lane >> 3;
  int scol = ((lane & 7) ^ srow) * 8;   // XOR swizzle on global side
  const unsigned short* gK = Kh + hq + (size_t)(wave * 16 + srow) * DK_ + scol;
  const _Float16* gV = Vt + ((size_t)bh * 64 + wave * 16 + srow) * S_ + scol;

  auto stage = [&](int o3, int kb) {
#pragma unroll
    for (int j = 0; j < 2; ++j) {
      __builtin_amdgcn_global_load_lds((gvp)(gK + (size_t)(kb * 64 + j * 8) * DK_),
          (lvp)(Ks + o3 + wave * 1024 + j * 512), 16, 0, 0);
      __builtin_amdgcn_global_load_lds((gvp)(gV + (size_t)(j * 8) * S_ + kb * 64),
          (lvp)(Vs + o3 + wave * 1024 + j * 512), 16, 0, 0);
    }
  };

  // prologue, order-pinned: [stage(0)] [mask(0)] [stage(1)]
  stage(0, 0);
  __builtin_amdgcn_sched_barrier(0);
  unsigned long long mw0c = mrow[0];
  unsigned long long mw1c = mrow[16 * (S_ / 64)];
  __builtin_amdgcn_sched_barrier(0);
  stage(4096, 1);

  int o0 = 0, o1 = 4096, o2 = 8192;   // rotating buffer offsets (ushort elements)

  constexpr int NK = S_ / 64;
  for (int i = 0; i < NK; ++i) {
    // newest 4 VMEM ops = stage(i+1); everything older (stage(i), mask(i)) retired.
    asm volatile("s_waitcnt vmcnt(4)" ::: "memory");
    __builtin_amdgcn_s_barrier();
    __builtin_amdgcn_sched_barrier(0);

    int nx1 = (i + 1 < NK) ? i + 1 : NK - 1;   // clamp: keep 6-op/iter invariant
    int nx2 = (i + 2 < NK) ? i + 2 : NK - 1;
    unsigned long long mw0n = mrow[nx1];
    unsigned long long mw1n = mrow[16 * (S_ / 64) + nx1];
    __builtin_amdgcn_sched_barrier(0);
    stage(o2, nx2);

    // K fragments from LDS (unswizzle)
    short8 bK[4][2];
#pragma unroll
    for (int t = 0; t < 4; ++t)
#pragma unroll
      for (int s2 = 0; s2 < 2; ++s2)
        bK[t][s2] = *(const short8*)(&Ks[o0 + (t * 16 + li) * 64 + (((s2 * 4 + quad) ^ (li & 7)) * 8)]);

    // V fragments from LDS (unswizzle)
    V8u vv[4][2];
#pragma unroll
    for (int dt = 0; dt < 4; ++dt)
#pragma unroll
      for (int tp = 0; tp < 2; ++tp)
        vv[dt][tp].v8 = *(const half8*)((const _Float16*)&Vs[o0 + (dt * 16 + li) * 64 + (((tp * 4 + quad) ^ (li & 7)) * 8)]);

    // scores transposed: lane holds S[q=li][k = i*64 + t*16 + quad*4 + r]
    floatx4 sc[4][2] = {};
    __builtin_amdgcn_s_setprio(1);
#pragma unroll
    for (int s2 = 0; s2 < 2; ++s2)
#pragma unroll
      for (int t = 0; t < 4; ++t)
#pragma unroll
        for (int qs = 0; qs < 2; ++qs)
          sc[t][qs] = __builtin_amdgcn_mfma_f32_16x16x32_bf16(bK[t][s2], aQ[qs][s2], sc[t][qs], 0, 0, 0);
    __builtin_amdgcn_s_setprio(0);

    unsigned long long sh0 = mw0c >> (quad * 4);
    unsigned long long sh1 = mw1c >> (quad * 4);

    // softmax without max-subtraction (exp2-domain scores):
    // P = exp2(s) packed to f16, then AND-masked via nibble LUT (masked lanes -> 0.0)
    uint2v aPu[4][2];
#pragma unroll
    for (int t = 0; t < 4; ++t)
#pragma unroll
      for (int qs = 0; qs < 2; ++qs) {
        unsigned nb = (unsigned)(((qs ? sh1 : sh0) >> (t * 16)) & 15u);
        uint2v mm = mlut[nb];
        float p0 = fexp2(sc[t][qs][0]);
        float p1 = fexp2(sc[t][qs][1]);
        float p2 = fexp2(sc[t][qs][2]);
        float p3 = fexp2(sc[t][qs][3]);
        uint2v pp;
        pp.x = __builtin_bit_cast(unsigned, pk_f16(p0, p1)) & mm.x;
        pp.y = __builtin_bit_cast(unsigned, pk_f16(p2, p3)) & mm.y;
        aPu[t][qs] = pp;
      }

    // PV + row-sum l on the MFMA pipe, K=32 f16 mfma (t-pairs merged)
    __builtin_amdgcn_s_setprio(1);
#pragma unroll
    for (int a = 0; a < 2; ++a)
#pragma unroll
      for (int qs = 0; qs < 2; ++qs) {
        half8 pa = mk8(aPu[2 * a][qs], aPu[2 * a + 1][qs]);
        lacc[qs] = __builtin_amdgcn_mfma_f32_16x16x32_f16(pa, ones8, lacc[qs], 0, 0, 0);
#pragma unroll
        for (int dt = 0; dt < 4; ++dt)
          o[qs][dt] = __builtin_amdgcn_mfma_f32_16x16x32_f16(pa, vv[dt][a].v8, o[qs][dt], 0, 0, 0);
      }
    __builtin_amdgcn_s_setprio(0);

    mw0c = mw0n; mw1c = mw1n;
    int tb = o0; o0 = o1; o1 = o2; o2 = tb;
  }

  // lacc[qs][r] = l for q-row (qs*16 + quad*4 + r), replicated across li -> no shuffles needed
#pragma unroll
  for (int qs = 0; qs < 2; ++qs)
#pragma unroll
    for (int r = 0; r < 4; ++r) {
      float ir = 1.0f / lacc[qs][r];
      size_t row = (size_t)b * S_ + qbase + qs * 16 + quad * 4 + r;
#pragma unroll
      for (int dt = 0; dt < 4; ++dt)
        attnb[row * D_ + h * DK_ + dt * 16 + li] = f2bf(o[qs][dt][r] * ir);
    }
}

// ---------- host ----------
extern "C" void kernel_launch(void* const* d_in, const int* in_sizes, int n_in,
                              void* d_out, int out_size, void* d_ws, size_t ws_size,
                              hipStream_t stream) {
  const float* query = (const float*)d_in[0];
  const float* key   = (const float*)d_in[1];
  const float* value = (const float*)d_in[2];
  const int*   mask  = (const int*)d_in[3];
  const float* Wq = (const float*)d_in[4];
  const float* bq = (const float*)d_in[5];
  const float* Wk = (const float*)d_in[6];
  const float* bk = (const float*)d_in[7];
  const float* Wv = (const float*)d_in[8];
  const float* bv = (const float*)d_in[9];
  const float* Wo = (const float*)d_in[10];
  const float* bo = (const float*)d_in[11];
  float* out = (float*)d_out;

  char* ws = (char*)d_ws;
  size_t off = 0;
  auto alloc = [&](size_t bytes) -> void* {
    void* p = ws + off;
    off += (bytes + 255) & ~(size_t)255;
    return p;
  };
  unsigned short* Xq    = (unsigned short*)alloc((size_t)BS_ * D_ * 2);
  unsigned short* Xk    = (unsigned short*)alloc((size_t)BS_ * D_ * 2);
  unsigned short* Xv    = (unsigned short*)alloc((size_t)BS_ * D_ * 2);
  unsigned short* Wqb   = (unsigned short*)alloc((size_t)D_ * D_ * 2);
  unsigned short* Wkb   = (unsigned short*)alloc((size_t)D_ * D_ * 2);
  unsigned short* Wvb   = (unsigned short*)alloc((size_t)D_ * D_ * 2);
  unsigned short* Wob   = (unsigned short*)alloc((size_t)D_ * D_ * 2);
  unsigned short* Qh    = (unsigned short*)alloc((size_t)BS_ * D_ * 2);
  unsigned short* Kh    = (unsigned short*)alloc((size_t)BS_ * D_ * 2);
  unsigned short* Vh    = (unsigned short*)alloc((size_t)BS_ * D_ * 2);  // f16 bits
  unsigned short* Vt    = (unsigned short*)alloc((size_t)BS_ * D_ * 2);  // f16 bits
  unsigned short* attnb = (unsigned short*)alloc((size_t)BS_ * D_ * 2);
  unsigned long long* mbits = (unsigned long long*)alloc((size_t)B_ * S_ * (S_ / 64) * 8);

  const float SC = 0.18033688011112042f;  // (1/8) * log2(e), folded into Q

  pack_mask<<<(B_ * S_ * S_) / 256, 256, 0, stream>>>(mask, mbits);

  int wn4 = D_ * D_ / 4;
  cast4_kernel<<<dim3(wn4 / 256, 4), 256, 0, stream>>>(Wq, Wk, Wv, Wo, Wqb, Wkb, Wvb, Wob, wn4);

  int xn4 = BS_ * D_ / 4;
  cast3_kernel<<<dim3(xn4 / 256, 3), 256, 0, stream>>>(query, key, value, Xq, Xk, Xv, xn4);

  gemm_qkv<<<dim3(D_ / 128, BS_ / 128, 3), 256, 0, stream>>>(
      Xq, Xk, Xv, Wqb, Wkb, Wvb, bq, bk, bv, Qh, Kh, Vh, SC);

  transpose_v<<<dim3(S_ / 64, B_ * H_), 256, 0, stream>>>(Vh, Vt);

  attn_kernel<<<dim3(8 * 8 * 16), 256, 0, stream>>>(Qh, Kh, (const _Float16*)Vt, mbits, attnb);

  gemm_out<<<dim3(D_ / 128, BS_ / 128), 256, 0, stream>>>(attnb, Wob, bo, out);
}

// Round 5
// 415.166 us; speedup vs baseline: 1.9174x; 1.0906x over previous
//
#include <hip/hip_runtime.h>

typedef __attribute__((ext_vector_type(8))) short short8;
typedef __attribute__((ext_vector_type(8))) unsigned short ushort8_t;
typedef __attribute__((ext_vector_type(4))) float floatx4;
typedef __attribute__((ext_vector_type(2))) _Float16 half2_t;
typedef __attribute__((ext_vector_type(4))) _Float16 half4;
typedef __attribute__((ext_vector_type(8))) _Float16 half8;
typedef __attribute__((ext_vector_type(2))) unsigned int uint2v;

#define B_ 4
#define S_ 2048
#define D_ 1024
#define H_ 16
#define DK_ 64
#define BS_ (B_ * S_)   // 8192
#define XN4_ (BS_ * D_ / 4)   // 2^21
#define WN4_ (D_ * D_ / 4)    // 2^18

union V8u { half8 v8; half4 v4[2]; };
union H16 { _Float16 h; unsigned short u; };

typedef const __attribute__((address_space(1))) void* gvp;
typedef __attribute__((address_space(3))) void* lvp;

// ---------- helpers ----------
static __device__ __forceinline__ unsigned short f2bf(float f) {
  union { float f; unsigned int u; } x; x.f = f;
  unsigned int r = x.u + 0x7fffu + ((x.u >> 16) & 1u);   // RNE
  return (unsigned short)(r >> 16);
}

static __device__ __forceinline__ half2_t pk_f16(float a, float b) {
  return __builtin_bit_cast(half2_t, __builtin_amdgcn_cvt_pkrtz(a, b));
}

// raw hardware exp2: avoids the OCML denormal-correct wrapper (~5x cheaper).
static __device__ __forceinline__ float fexp2(float x) {
  float r;
  asm("v_exp_f32 %0, %1" : "=v"(r) : "v"(x));
  return r;
}

static __device__ __forceinline__ half8 mk8(uint2v a, uint2v b) {
  union { unsigned u[4]; half8 h; } t;
  t.u[0] = a.x; t.u[1] = a.y; t.u[2] = b.x; t.u[3] = b.y;
  return t.h;
}

// ---------- single fused cast: 3 X arrays (2^21 float4 each) + 4 W arrays (2^18 each) ----------
__global__ void cast_all(const float* __restrict__ q, const float* __restrict__ k,
                         const float* __restrict__ v,
                         const float* __restrict__ wq, const float* __restrict__ wk,
                         const float* __restrict__ wv, const float* __restrict__ wo,
                         unsigned short* __restrict__ oq, unsigned short* __restrict__ ok,
                         unsigned short* __restrict__ ov,
                         unsigned short* __restrict__ owq, unsigned short* __restrict__ owk,
                         unsigned short* __restrict__ owv, unsigned short* __restrict__ owo) {
  int i = blockIdx.x * blockDim.x + threadIdx.x;
  const float* src; unsigned short* dst; int j;
  if (i < 3 * XN4_) {
    int w = i >> 21; j = i & (XN4_ - 1);
    src = (w == 0) ? q : (w == 1) ? k : v;
    dst = (w == 0) ? oq : (w == 1) ? ok : ov;
  } else {
    int t = i - 3 * XN4_;
    int w = t >> 18; j = t & (WN4_ - 1);
    src = (w == 0) ? wq : (w == 1) ? wk : (w == 2) ? wv : wo;
    dst = (w == 0) ? owq : (w == 1) ? owk : (w == 2) ? owv : owo;
  }
  float4 v4 = ((const float4*)src)[j];
  ushort4 o;
  o.x = f2bf(v4.x); o.y = f2bf(v4.y); o.z = f2bf(v4.z); o.w = f2bf(v4.w);
  ((ushort4*)dst)[j] = o;
}

// ---------- mask int32 -> bitmask (bit=1 means keep) ----------
__global__ void pack_mask(const int* __restrict__ mask, unsigned long long* __restrict__ bits) {
  int i = blockIdx.x * blockDim.x + threadIdx.x;
  unsigned long long m = __ballot(mask[i] != 0);
  if ((threadIdx.x & 63) == 0) bits[i >> 6] = m;
}

// ---------- pipelined GEMM core: Y = scale*(X(Mx1024) * W(1024x1024)^T + bias) ----------
// mode 0: bf16 out head layout [bh][s][dk]
// mode 1: fp32 out row-major
// mode 3: f16 out transposed+k-permuted head layout Vt[bh*64+dk][s] (fuses old transpose_v)
__device__ __forceinline__ void gemm_core(
    const unsigned short* __restrict__ X, const unsigned short* __restrict__ W,
    const float* __restrict__ bias, void* __restrict__ Y,
    float scale, int mode, int bm, int bn,
    unsigned short* As, unsigned short* Bs)
{
  constexpr int K = D_, N = D_;
  int tid = threadIdx.x;
  int wave = tid >> 6, lane = tid & 63, quad = lane >> 4, li = lane & 15;
  int wm = wave >> 1, wn = wave & 1;
  int srow = lane >> 3;
  int scol = ((lane & 7) ^ srow) * 8;   // XOR swizzle on global side
  const unsigned short* gA = X + (size_t)(bm * 128 + wave * 32 + srow) * K + scol;
  const unsigned short* gB = W + (size_t)(bn * 128 + wave * 32 + srow) * K + scol;

  auto stage = [&](int buf, int k0) {
#pragma unroll
    for (int j = 0; j < 4; ++j) {
      __builtin_amdgcn_global_load_lds((gvp)(gA + (size_t)(j * 8) * K + k0),
          (lvp)(As + buf * 8192 + wave * 2048 + j * 512), 16, 0, 0);
      __builtin_amdgcn_global_load_lds((gvp)(gB + (size_t)(j * 8) * K + k0),
          (lvp)(Bs + buf * 8192 + wave * 2048 + j * 512), 16, 0, 0);
    }
  };

  floatx4 acc[4][4] = {};
  stage(0, 0);
  constexpr int NK = K / 64;
  for (int i = 0; i < NK; ++i) {
    int buf = i & 1;
    __syncthreads();                       // buf data valid; prev prefetch already landed
    if (i + 1 < NK) stage(buf ^ 1, (i + 1) * 64);   // prefetch next tile (hidden behind compute)
    short8 af[2][4], bf[2][4];
#pragma unroll
    for (int s2 = 0; s2 < 2; ++s2)
#pragma unroll
      for (int t = 0; t < 4; ++t) {
        int slot = ((s2 * 4 + quad) ^ (li & 7)) * 8;
        af[s2][t] = *(const short8*)(&As[buf * 8192 + (wm * 64 + t * 16 + li) * 64 + slot]);
        bf[s2][t] = *(const short8*)(&Bs[buf * 8192 + (wn * 64 + t * 16 + li) * 64 + slot]);
      }
#pragma unroll
    for (int s2 = 0; s2 < 2; ++s2)
#pragma unroll
      for (int mt = 0; mt < 4; ++mt)
#pragma unroll
        for (int nt = 0; nt < 4; ++nt)
          acc[mt][nt] = __builtin_amdgcn_mfma_f32_16x16x32_bf16(af[s2][mt], bf[s2][nt], acc[mt][nt], 0, 0, 0);
  }

  if (mode == 3) {
    // V -> Vt fused transpose. For row m = mbase + mt*16 + quad*4 + r (mbase 64-aligned),
    // the k-permuted position is pos = (mt>>1)*32 + quad*8 + (mt&1)*4 + r  (verified:
    // forward map k(pos) == m&63). r-quads are contiguous -> one 8B store per (mt,nt).
    int mbase = bm * 128 + wm * 64;
    int b0 = mbase >> 11;
    int sblk = mbase & 2047;            // 64-aligned s-block base
#pragma unroll
    for (int nt = 0; nt < 4; ++nt) {
      int n = bn * 128 + wn * 64 + nt * 16 + li;
      float bv = bias[n];
      int h = n >> 6, dk = n & 63;
#pragma unroll
      for (int mt = 0; mt < 4; ++mt) {
        int pos = (mt >> 1) * 32 + quad * 8 + (mt & 1) * 4;
        H16 h0, h1, h2, h3;
        h0.h = (_Float16)(acc[mt][nt][0] + bv);
        h1.h = (_Float16)(acc[mt][nt][1] + bv);
        h2.h = (_Float16)(acc[mt][nt][2] + bv);
        h3.h = (_Float16)(acc[mt][nt][3] + bv);
        uint2v pk;
        pk.x = (unsigned)h0.u | ((unsigned)h1.u << 16);
        pk.y = (unsigned)h2.u | ((unsigned)h3.u << 16);
        size_t idx = (((size_t)(b0 * H_ + h)) * DK_ + dk) * S_ + sblk + pos;
        *(uint2v*)((unsigned short*)Y + idx) = pk;
      }
    }
    return;
  }

#pragma unroll
  for (int nt = 0; nt < 4; ++nt) {
    int n = bn * 128 + wn * 64 + nt * 16 + li;
    float bv = bias[n];
#pragma unroll
    for (int mt = 0; mt < 4; ++mt) {
#pragma unroll
      for (int r = 0; r < 4; ++r) {
        int m = bm * 128 + wm * 64 + mt * 16 + quad * 4 + r;
        float v = (acc[mt][nt][r] + bv) * scale;
        if (mode == 1) {
          ((float*)Y)[(size_t)m * N + n] = v;
        } else {
          int b = m >> 11, s = m & 2047, h = n >> 6, dk = n & 63;
          size_t idx = (((size_t)(b * H_ + h)) * S_ + s) * DK_ + dk;
          ((unsigned short*)Y)[idx] = f2bf(v);
        }
      }
    }
  }
}

__global__ __launch_bounds__(256) void gemm_qkv(
    const unsigned short* __restrict__ Xq, const unsigned short* __restrict__ Xk,
    const unsigned short* __restrict__ Xv,
    const unsigned short* __restrict__ Wq, const unsigned short* __restrict__ Wk,
    const unsigned short* __restrict__ Wv,
    const float* __restrict__ bq, const float* __restrict__ bk, const float* __restrict__ bv,
    unsigned short* __restrict__ Qh, unsigned short* __restrict__ Kh,
    unsigned short* __restrict__ Vt, float sc)
{
  __shared__ __align__(16) unsigned short As[2 * 8192];
  __shared__ __align__(16) unsigned short Bs[2 * 8192];
  int z = blockIdx.z;
  const unsigned short* X = (z == 0) ? Xq : (z == 1) ? Xk : Xv;
  const unsigned short* W = (z == 0) ? Wq : (z == 1) ? Wk : Wv;
  const float* bias = (z == 0) ? bq : (z == 1) ? bk : bv;
  void* Y = (z == 0) ? (void*)Qh : (z == 1) ? (void*)Kh : (void*)Vt;
  float scale = (z == 0) ? sc : 1.0f;
  int mode = (z == 2) ? 3 : 0;
  gemm_core(X, W, bias, Y, scale, mode, blockIdx.y, blockIdx.x, As, Bs);
}

__global__ __launch_bounds__(256) void gemm_out(
    const unsigned short* __restrict__ X, const unsigned short* __restrict__ W,
    const float* __restrict__ bias, float* __restrict__ Y)
{
  __shared__ __align__(16) unsigned short As[2 * 8192];
  __shared__ __align__(16) unsigned short Bs[2 * 8192];
  gemm_core(X, W, bias, Y, 1.0f, 1, blockIdx.y, blockIdx.x, As, Bs);
}

// ---------- flash attention: pipelined dbuf LDS K/V tiles, transposed-score softmax ----------
// (R2 version: best measured structure — dbuf + __syncthreads, K=32 f16 PV, LUT mask,
//  raw v_exp, l via ones-mfma. R3/R4 counted-vmcnt variants measured slower.)
__global__ __launch_bounds__(256) void attn_kernel(
    const unsigned short* __restrict__ Qh,
    const unsigned short* __restrict__ Kh,
    const _Float16* __restrict__ Vt,
    const unsigned long long* __restrict__ mbits,
    unsigned short* __restrict__ attnb)
{
  __shared__ __align__(16) unsigned short Ks[2 * 4096];
  __shared__ __align__(16) unsigned short Vs[2 * 4096];
  __shared__ __align__(8) uint2v mlut[16];   // nibble -> 2x32b AND-masks for packed f16 pairs

  int tid = threadIdx.x;
  int wave = tid >> 6, lane = tid & 63, quad = lane >> 4, li = lane & 15;

  if (tid < 16) {
    unsigned nb = (unsigned)tid;
    uint2v m;
    m.x = (nb & 1u ? 0x0000FFFFu : 0u) | (nb & 2u ? 0xFFFF0000u : 0u);
    m.y = (nb & 4u ? 0x0000FFFFu : 0u) | (nb & 8u ? 0xFFFF0000u : 0u);
    mlut[nb] = m;
  }

  int blk = blockIdx.x;
  int xcd = blk & 7, slot7 = blk >> 3;
  int bh = xcd * 8 + (slot7 >> 4);
  int qb = slot7 & 15;
  int b = bh >> 4, h = bh & 15;
  int qbase = qb * 128 + wave * 32;
  const size_t hq = (size_t)bh * S_ * DK_;

  // Q fragments (B-operand of S^T mfma), loaded once from global
  short8 aQ[2][2];
#pragma unroll
  for (int qs = 0; qs < 2; ++qs)
#pragma unroll
    for (int s2 = 0; s2 < 2; ++s2)
      aQ[qs][s2] = *(const short8*)(Qh + hq + (size_t)(qbase + qs * 16 + li) * DK_ + s2 * 32 + quad * 8);

  floatx4 o[2][4] = {};
  floatx4 lacc[2] = {};
  const half8 ones8 = {(_Float16)1.f, (_Float16)1.f, (_Float16)1.f, (_Float16)1.f,
                       (_Float16)1.f, (_Float16)1.f, (_Float16)1.f, (_Float16)1.f};

  const unsigned long long* mrow = mbits + ((size_t)b * S_ + qbase + li) * (S_ / 64);

  // staging: wave w covers rows w*16..w*16+15; call j covers 8 rows
  int srow = lane >> 3;
  int scol = ((lane & 7) ^ srow) * 8;   // XOR swizzle on global side
  const unsigned short* gK = Kh + hq + (size_t)(wave * 16 + srow) * DK_ + scol;
  const _Float16* gV = Vt + ((size_t)bh * 64 + wave * 16 + srow) * S_ + scol;

  auto stage = [&](int buf, int k0) {
#pragma unroll
    for (int j = 0; j < 2; ++j) {
      __builtin_amdgcn_global_load_lds((gvp)(gK + (size_t)(k0 + j * 8) * DK_),
          (lvp)(Ks + buf * 4096 + wave * 1024 + j * 512), 16, 0, 0);
      __builtin_amdgcn_global_load_lds((gvp)(gV + (size_t)(j * 8) * S_ + k0),
          (lvp)(Vs + buf * 4096 + wave * 1024 + j * 512), 16, 0, 0);
    }
  };

  stage(0, 0);
  unsigned long long mw0c = mrow[0];
  unsigned long long mw1c = mrow[16 * (S_ / 64)];

  constexpr int NK = S_ / 64;
#pragma unroll 2
  for (int i = 0; i < NK; ++i) {
    int buf = i & 1;
    __syncthreads();                        // buf valid; prev prefetch landed during compute
    if (i + 1 < NK) stage(buf ^ 1, (i + 1) * 64);   // prefetch next K/V tile
    unsigned long long mw0n = 0, mw1n = 0;
    if (i + 1 < NK) { mw0n = mrow[i + 1]; mw1n = mrow[16 * (S_ / 64) + i + 1]; }

    // K fragments from LDS (unswizzle)
    short8 bK[4][2];
#pragma unroll
    for (int t = 0; t < 4; ++t)
#pragma unroll
      for (int s2 = 0; s2 < 2; ++s2)
        bK[t][s2] = *(const short8*)(&Ks[buf * 4096 + (t * 16 + li) * 64 + (((s2 * 4 + quad) ^ (li & 7)) * 8)]);

    // V fragments from LDS (unswizzle)
    V8u vv[4][2];
#pragma unroll
    for (int dt = 0; dt < 4; ++dt)
#pragma unroll
      for (int tp = 0; tp < 2; ++tp)
        vv[dt][tp].v8 = *(const half8*)((const _Float16*)&Vs[buf * 4096 + (dt * 16 + li) * 64 + (((tp * 4 + quad) ^ (li & 7)) * 8)]);

    // scores transposed: lane holds S[q=li][k = i*64 + t*16 + quad*4 + r]
    floatx4 sc[4][2] = {};
    __builtin_amdgcn_s_setprio(1);
#pragma unroll
    for (int s2 = 0; s2 < 2; ++s2)
#pragma unroll
      for (int t = 0; t < 4; ++t)
#pragma unroll
        for (int qs = 0; qs < 2; ++qs)
          sc[t][qs] = __builtin_amdgcn_mfma_f32_16x16x32_bf16(bK[t][s2], aQ[qs][s2], sc[t][qs], 0, 0, 0);
    __builtin_amdgcn_s_setprio(0);

    unsigned long long sh0 = mw0c >> (quad * 4);
    unsigned long long sh1 = mw1c >> (quad * 4);

    // softmax without max-subtraction (exp2-domain scores):
    // P = exp2(s) packed to f16, then AND-masked via nibble LUT (masked lanes -> 0.0)
    uint2v aPu[4][2];
#pragma unroll
    for (int t = 0; t < 4; ++t)
#pragma unroll
      for (int qs = 0; qs < 2; ++qs) {
        unsigned nb = (unsigned)(((qs ? sh1 : sh0) >> (t * 16)) & 15u);
        uint2v mm = mlut[nb];
        float p0 = fexp2(sc[t][qs][0]);
        float p1 = fexp2(sc[t][qs][1]);
        float p2 = fexp2(sc[t][qs][2]);
        float p3 = fexp2(sc[t][qs][3]);
        uint2v pp;
        pp.x = __builtin_bit_cast(unsigned, pk_f16(p0, p1)) & mm.x;
        pp.y = __builtin_bit_cast(unsigned, pk_f16(p2, p3)) & mm.y;
        aPu[t][qs] = pp;
      }

    // PV + row-sum l on the MFMA pipe, K=32 f16 mfma (t-pairs merged)
    __builtin_amdgcn_s_setprio(1);
#pragma unroll
    for (int a = 0; a < 2; ++a)
#pragma unroll
      for (int qs = 0; qs < 2; ++qs) {
        half8 pa = mk8(aPu[2 * a][qs], aPu[2 * a + 1][qs]);
        lacc[qs] = __builtin_amdgcn_mfma_f32_16x16x32_f16(pa, ones8, lacc[qs], 0, 0, 0);
#pragma unroll
        for (int dt = 0; dt < 4; ++dt)
          o[qs][dt] = __builtin_amdgcn_mfma_f32_16x16x32_f16(pa, vv[dt][a].v8, o[qs][dt], 0, 0, 0);
      }
    __builtin_amdgcn_s_setprio(0);

    mw0c = mw0n; mw1c = mw1n;
  }

  // lacc[qs][r] = l for q-row (qs*16 + quad*4 + r), replicated across li -> no shuffles needed
#pragma unroll
  for (int qs = 0; qs < 2; ++qs)
#pragma unroll
    for (int r = 0; r < 4; ++r) {
      float ir = 1.0f / lacc[qs][r];
      size_t row = (size_t)b * S_ + qbase + qs * 16 + quad * 4 + r;
#pragma unroll
      for (int dt = 0; dt < 4; ++dt)
        attnb[row * D_ + h * DK_ + dt * 16 + li] = f2bf(o[qs][dt][r] * ir);
    }
}

// ---------- host ----------
extern "C" void kernel_launch(void* const* d_in, const int* in_sizes, int n_in,
                              void* d_out, int out_size, void* d_ws, size_t ws_size,
                              hipStream_t stream) {
  const float* query = (const float*)d_in[0];
  const float* key   = (const float*)d_in[1];
  const float* value = (const float*)d_in[2];
  const int*   mask  = (const int*)d_in[3];
  const float* Wq = (const float*)d_in[4];
  const float* bq = (const float*)d_in[5];
  const float* Wk = (const float*)d_in[6];
  const float* bk = (const float*)d_in[7];
  const float* Wv = (const float*)d_in[8];
  const float* bv = (const float*)d_in[9];
  const float* Wo = (const float*)d_in[10];
  const float* bo = (const float*)d_in[11];
  float* out = (float*)d_out;

  char* ws = (char*)d_ws;
  size_t off = 0;
  auto alloc = [&](size_t bytes) -> void* {
    void* p = ws + off;
    off += (bytes + 255) & ~(size_t)255;
    return p;
  };
  unsigned short* Xq    = (unsigned short*)alloc((size_t)BS_ * D_ * 2);
  unsigned short* Xk    = (unsigned short*)alloc((size_t)BS_ * D_ * 2);
  unsigned short* Xv    = (unsigned short*)alloc((size_t)BS_ * D_ * 2);
  unsigned short* Wqb   = (unsigned short*)alloc((size_t)D_ * D_ * 2);
  unsigned short* Wkb   = (unsigned short*)alloc((size_t)D_ * D_ * 2);
  unsigned short* Wvb   = (unsigned short*)alloc((size_t)D_ * D_ * 2);
  unsigned short* Wob   = (unsigned short*)alloc((size_t)D_ * D_ * 2);
  unsigned short* Qh    = (unsigned short*)alloc((size_t)BS_ * D_ * 2);
  unsigned short* Kh    = (unsigned short*)alloc((size_t)BS_ * D_ * 2);
  unsigned short* Vt    = (unsigned short*)alloc((size_t)BS_ * D_ * 2);  // f16 bits, transposed
  unsigned short* attnb = (unsigned short*)alloc((size_t)BS_ * D_ * 2);
  unsigned long long* mbits = (unsigned long long*)alloc((size_t)B_ * S_ * (S_ / 64) * 8);

  const float SC = 0.18033688011112042f;  // (1/8) * log2(e), folded into Q

  pack_mask<<<(B_ * S_ * S_) / 256, 256, 0, stream>>>(mask, mbits);

  cast_all<<<(3 * XN4_ + 4 * WN4_) / 256, 256, 0, stream>>>(
      query, key, value, Wq, Wk, Wv, Wo,
      Xq, Xk, Xv, Wqb, Wkb, Wvb, Wob);

  gemm_qkv<<<dim3(D_ / 128, BS_ / 128, 3), 256, 0, stream>>>(
      Xq, Xk, Xv, Wqb, Wkb, Wvb, bq, bk, bv, Qh, Kh, Vt, SC);

  attn_kernel<<<dim3(8 * 8 * 16), 256, 0, stream>>>(Qh, Kh, (const _Float16*)Vt, mbits, attnb);

  gemm_out<<<dim3(D_ / 128, BS_ / 128), 256, 0, stream>>>(attnb, Wob, bo, out);
}